// Round 9
// baseline (159.055 us; speedup 1.0000x reference)
//
#include <hip/hip_runtime.h>

typedef _Float16 half8  __attribute__((ext_vector_type(8)));
typedef _Float16 half4v __attribute__((ext_vector_type(4)));
typedef float    floatx4 __attribute__((ext_vector_type(4)));

#define K_DIM 2312
#define KP    2368          // W1 fp16 padded K (74*32)
#define N_DIM 1024
#define M_DIM 16384
#define T_DIM 16
#define O_DIM 10
#define NKT   73            // BK=32 tiles covering 2312 (tile 72 partial)
#define NT_OLD 73
#define LDP 40

// =====================================================================
// cvt: fp32 -> fp16 with K zero-pad to 2368 (W1 only; pad MUST be zero --
// tile-72 A garbage relies on B==0 for k in [2312,2336))
// =====================================================================
__global__ __launch_bounds__(256) void cvt_f32_f16_pad(const float* __restrict__ src,
                                                       _Float16* __restrict__ dst) {
  int row = blockIdx.x;
  const float* s = src + (size_t)row * K_DIM;
  _Float16* d = dst + (size_t)row * KP;
  for (int c = threadIdx.x; c < 296; c += 256) {
    half8 o;
    if (c < 289) {
      floatx4 a = *(const floatx4*)(s + c * 8);
      floatx4 b = *(const floatx4*)(s + c * 8 + 4);
      #pragma unroll
      for (int e = 0; e < 4; ++e) { o[e] = (_Float16)a[e]; o[4 + e] = (_Float16)b[e]; }
    } else {
      o = half8{0, 0, 0, 0, 0, 0, 0, 0};
    }
    *(half8*)(d + c * 8) = o;
  }
}

// =====================================================================
// GEMM: h = x(fp32) @ w1h^T + b1. 256x256, BK=32, 8 waves (4M x 2N).
// m201-style 4-phase K-loop: per phase {ds_reads + 2 DMAs, BAR, lgkm(0),
// setprio 8xMFMA, BAR}; vmcnt(6) publish at P4 (counted, never 0).
// A in LDS as 512 half-rows x 16 floats (64B stride, B-style layout ->
// bank quad depends on row; position key = row&3, both-sides involution):
//   write: DMA linear; lane l2=lane&3 slot holds source chunk l2^((rlo>>1)&3)
//   read : off = row*32 + (q>>1)*16 + ((2(q&1)+e) ^ (row&3))*4
// A converted fp32->fp16 on the read path (RTN, same numerics as R8).
// =====================================================================
__device__ __forceinline__ void gload16(const void* g, void* l) {
  __builtin_amdgcn_global_load_lds((const __attribute__((address_space(1))) void*)g,
                                   (__attribute__((address_space(3))) void*)l, 16, 0, 0);
}

#define VMCNT(n)  asm volatile("s_waitcnt vmcnt(" #n ")" ::: "memory")
#define LGKM0     asm volatile("s_waitcnt lgkmcnt(0)" ::: "memory")
#define SBAR      __builtin_amdgcn_sched_barrier(0)
#define BARRIER   __builtin_amdgcn_s_barrier()

__global__ __launch_bounds__(512, 2) void gemm_fused4(const float* __restrict__ X,
                                                      const _Float16* __restrict__ Bw,
                                                      const float* __restrict__ b1,
                                                      float* __restrict__ h) {
  __shared__ __align__(16) float    As[3][256 * 32];   // 3 x 32 KiB (fp32 A, half-row layout)
  __shared__ __align__(16) _Float16 Bs[3][256 * 32];   // 3 x 16 KiB (fp16 B)

  const int tid  = threadIdx.x;
  const int lane = tid & 63;
  const int w    = tid >> 6;          // 0..7
  const int wm   = (w >> 1) * 64;     // 4 row-waves
  const int wn   = (w & 1) * 128;     // 2 col-waves
  const int bm   = blockIdx.x & 63;
  const int bn   = blockIdx.x >> 6;
  const int m0   = bm * 256;
  const int n0   = bn * 256;

  // ---- A staging: 4 DMAs/wave; DMA d covers half-rows (w*4+d)*16..+15 ----
  const int rlo  = lane >> 2;                       // 0..15: half-row within DMA
  const int l2   = lane & 3;                        // 16B slot within half-row
  const int hpA  = (rlo & 1) * 16 + (l2 ^ ((rlo >> 1) & 3)) * 4;  // k-offset in row
  const float* xrow[4];
  #pragma unroll
  for (int d = 0; d < 4; ++d)
    xrow[d] = X + (size_t)(m0 + w * 32 + d * 8 + (rlo >> 1)) * K_DIM;

  // ---- B staging (proven R5 pattern) ----
  const int keyB = (rlo >> 1) & 3;
  const int cch  = l2 ^ keyB;
  const _Float16* bg = Bw + (size_t)(n0 + w * 32 + rlo) * KP + cch * 8;
  const int stbB = (w * 32) * 32;

  floatx4 acc[4][8];
  #pragma unroll
  for (int i = 0; i < 4; ++i)
    #pragma unroll
    for (int j = 0; j < 8; ++j)
      acc[i][j] = floatx4{0.f, 0.f, 0.f, 0.f};

  // ---- fragment read offsets ----
  const int fr = lane & 15;
  const int q  = lane >> 4;           // 0..3
  const int rdsB = (q ^ ((fr >> 1) & 3)) * 8;       // B swizzled 16B slot (halfs)
  int offB[8];
  #pragma unroll
  for (int j = 0; j < 8; ++j) offB[j] = (wn + j * 16 + fr) * 32 + rdsB;
  int offA[8];                                       // [2i+e], floats
  #pragma unroll
  for (int i = 0; i < 4; ++i) {
    const int rowA = wm + i * 16 + fr;
    #pragma unroll
    for (int e = 0; e < 2; ++e)
      offA[2 * i + e] = rowA * 32 + (q >> 1) * 16 + ((2 * (q & 1) + e) ^ (rowA & 3)) * 4;
  }

  floatx4 fA[8];     // raw fp32 A frags (frag i = fA[2i], fA[2i+1])
  half8   bf[8];

#define DMA_A(tk, d) do {                                                    \
    int _kk = (tk) * 32 + hpA; _kk = _kk > 2308 ? 2308 : _kk;                \
    gload16(xrow[d] + _kk, &As[(tk) % 3][(w * 4 + (d)) * 256]);              \
  } while (0)
#define DMA_B(tk, half) do {                                                 \
    gload16(bg + (tk) * 32 + (half) * 16 * KP,                               \
            &Bs[(tk) % 3][stbB + (half) * 16 * 32]);                         \
  } while (0)
#define RD_A(tk, ih) do { const float* _A = As[(tk) % 3];                    \
    fA[4*(ih)+0] = *(const floatx4*)(&_A[offA[4*(ih)+0]]);                   \
    fA[4*(ih)+1] = *(const floatx4*)(&_A[offA[4*(ih)+1]]);                   \
    fA[4*(ih)+2] = *(const floatx4*)(&_A[offA[4*(ih)+2]]);                   \
    fA[4*(ih)+3] = *(const floatx4*)(&_A[offA[4*(ih)+3]]); } while (0)
#define RD_B(tk, jh) do { const _Float16* _B = Bs[(tk) % 3];                 \
    _Pragma("unroll")                                                        \
    for (int _j = 0; _j < 4; ++_j)                                           \
      bf[4*(jh)+_j] = *(const half8*)(&_B[offB[4*(jh)+_j]]); } while (0)
#define MQ(ih, jh) do {                                                      \
    __builtin_amdgcn_s_setprio(1);                                           \
    _Pragma("unroll")                                                        \
    for (int _i = 2*(ih); _i < 2*(ih)+2; ++_i) {                             \
      half8 _ah;                                                             \
      _Pragma("unroll")                                                      \
      for (int _e = 0; _e < 4; ++_e) {                                       \
        _ah[_e]     = (_Float16)fA[2*_i][_e];                                \
        _ah[4+_e]   = (_Float16)fA[2*_i+1][_e];                              \
      }                                                                      \
      _Pragma("unroll")                                                      \
      for (int _j = 4*(jh); _j < 4*(jh)+4; ++_j)                             \
        acc[_i][_j] = __builtin_amdgcn_mfma_f32_16x16x32_f16(_ah, bf[_j], acc[_i][_j], 0, 0, 0); \
    }                                                                        \
    __builtin_amdgcn_s_setprio(0);                                           \
  } while (0)

  // ---- prologue: stage tiles 0,1 (FIFO: A0x4,B0x2,A1x4,B1x2); publish 0 ----
  DMA_A(0,0); DMA_A(0,1); DMA_A(0,2); DMA_A(0,3); DMA_B(0,0); DMA_B(0,1);
  DMA_A(1,0); DMA_A(1,1); DMA_A(1,2); DMA_A(1,3); DMA_B(1,0); DMA_B(1,1);
  VMCNT(6); SBAR;              // tile 0's 6 DMAs retired
  BARRIER; SBAR;

  // ---- main loop: 4 phases per tile ----
  for (int t = 0; t < NKT; ++t) {
    const bool st = (t + 2 < NKT);
    // P1: read fA0 + bf0 of tile t; issue A(t+2) d0,d1
    RD_A(t, 0); RD_B(t, 0);
    if (st) { DMA_A(t + 2, 0); DMA_A(t + 2, 1); }
    BARRIER; LGKM0; SBAR;
    MQ(0, 0);                  // Q00
    BARRIER; SBAR;
    // P2: read bf1; issue A(t+2) d2,d3
    RD_B(t, 1);
    if (st) { DMA_A(t + 2, 2); DMA_A(t + 2, 3); }
    BARRIER; LGKM0; SBAR;
    MQ(0, 1);                  // Q01
    BARRIER; SBAR;
    // P3: read fA1; issue B(t+2)
    RD_A(t, 1);
    if (st) { DMA_B(t + 2, 0); DMA_B(t + 2, 1); }
    BARRIER; LGKM0; SBAR;
    MQ(1, 1);                  // Q11
    BARRIER; SBAR;
    // P4: counted publish of tile t+1, then Q10
    if (st) { VMCNT(6); } else { VMCNT(0); }
    SBAR;
    BARRIER; SBAR;             // publish tile t+1 (vmcnt before barrier)
    MQ(1, 0);                  // Q10
    BARRIER; SBAR;
  }

#undef DMA_A
#undef DMA_B
#undef RD_A
#undef RD_B
#undef MQ

  // ---- epilogue: C/D layout col = lane&15, row = (lane>>4)*4 + reg ----
  const int cr = (lane >> 4) * 4;
  #pragma unroll
  for (int j = 0; j < 8; ++j) {
    int col = n0 + wn + j * 16 + fr;
    float bv = b1[col];
    #pragma unroll
    for (int i = 0; i < 4; ++i) {
      int rbase = m0 + wm + i * 16 + cr;
      #pragma unroll
      for (int e = 0; e < 4; ++e)
        h[(size_t)(rbase + e) * N_DIM + col] = acc[i][j][e] + bv;
    }
  }
}

// =====================================================================
// Fallback (R1): reg-staged fp32->fp16 GEMM, used only if ws too small
// =====================================================================
__device__ __forceinline__ void stage_load(const float* __restrict__ x,
                                           const float* __restrict__ w,
                                           int m0, int n0, int k0, int tid,
                                           floatx4 (&ar)[4], floatx4 (&br)[4]) {
  int r = tid >> 3;
  int c = (tid & 7) * 4;
  bool ok = (k0 + c) < K_DIM;
  #pragma unroll
  for (int i = 0; i < 4; ++i) {
    int row = r + 32 * i;
    if (ok) {
      ar[i] = *(const floatx4*)(x + (size_t)(m0 + row) * K_DIM + k0 + c);
      br[i] = *(const floatx4*)(w + (size_t)(n0 + row) * K_DIM + k0 + c);
    } else {
      ar[i] = floatx4{0.f, 0.f, 0.f, 0.f};
      br[i] = floatx4{0.f, 0.f, 0.f, 0.f};
    }
  }
}

__device__ __forceinline__ void stage_write(_Float16* __restrict__ Ab,
                                            _Float16* __restrict__ Bb, int tid,
                                            const floatx4 (&ar)[4], const floatx4 (&br)[4]) {
  int r = tid >> 3;
  int c = (tid & 7) * 4;
  #pragma unroll
  for (int i = 0; i < 4; ++i) {
    int row = r + 32 * i;
    half4v av, bv;
    #pragma unroll
    for (int e = 0; e < 4; ++e) {
      av[e] = (_Float16)ar[i][e];
      bv[e] = (_Float16)br[i][e];
    }
    *(half4v*)(Ab + row * LDP + c) = av;
    *(half4v*)(Bb + row * LDP + c) = bv;
  }
}

__global__ __launch_bounds__(256) void gemm1_kernel(const float* __restrict__ x,
                                                    const float* __restrict__ W1,
                                                    const float* __restrict__ b1,
                                                    float* __restrict__ h) {
  __shared__ _Float16 Al[2][128 * LDP];
  __shared__ _Float16 Bl[2][128 * LDP];

  int tid  = threadIdx.x;
  int lane = tid & 63;
  int w    = tid >> 6;
  int wm   = (w >> 1) * 64;
  int wn   = (w & 1) * 64;
  int m0   = (blockIdx.x >> 3) * 128;
  int n0   = (blockIdx.x & 7) * 128;

  floatx4 acc[4][4];
  #pragma unroll
  for (int i = 0; i < 4; ++i)
    #pragma unroll
    for (int j = 0; j < 4; ++j)
      acc[i][j] = floatx4{0.f, 0.f, 0.f, 0.f};

  floatx4 ar[4], br[4];
  stage_load(x, W1, m0, n0, 0, tid, ar, br);
  stage_write(Al[0], Bl[0], tid, ar, br);
  __syncthreads();

  int fr = lane & 15;
  int kc = (lane >> 4) * 8;

  int cur = 0;
  for (int kt = 0; kt < NT_OLD; ++kt) {
    if (kt + 1 < NT_OLD) stage_load(x, W1, m0, n0, (kt + 1) * 32, tid, ar, br);

    const _Float16* Ab = Al[cur];
    const _Float16* Bb = Bl[cur];
    half8 af[4], bf[4];
    #pragma unroll
    for (int f = 0; f < 4; ++f) {
      af[f] = *(const half8*)(Ab + (wm + f * 16 + fr) * LDP + kc);
      bf[f] = *(const half8*)(Bb + (wn + f * 16 + fr) * LDP + kc);
    }
    #pragma unroll
    for (int i = 0; i < 4; ++i)
      #pragma unroll
      for (int j = 0; j < 4; ++j)
        acc[i][j] = __builtin_amdgcn_mfma_f32_16x16x32_f16(af[i], bf[j], acc[i][j], 0, 0, 0);

    if (kt + 1 < NT_OLD) stage_write(Al[cur ^ 1], Bl[cur ^ 1], tid, ar, br);
    __syncthreads();
    cur ^= 1;
  }

  int cr = (lane >> 4) * 4;
  #pragma unroll
  for (int j = 0; j < 4; ++j) {
    int col = n0 + wn + j * 16 + fr;
    float bv = b1[col];
    #pragma unroll
    for (int i = 0; i < 4; ++i) {
      int rbase = m0 + wm + i * 16 + cr;
      #pragma unroll
      for (int e = 0; e < 4; ++e)
        h[(size_t)(rbase + e) * N_DIM + col] = acc[i][j][e] + bv;
    }
  }
}

// =====================================================================
// temporal LIF chain, one wave per batch row
// =====================================================================
__global__ __launch_bounds__(256) void snn_temporal_kernel(const float* __restrict__ h,
                                                           const float* __restrict__ W2,
                                                           const float* __restrict__ b2,
                                                           float* __restrict__ out) {
  __shared__ float w2s[O_DIM * N_DIM];   // 40 KB
  int tid = threadIdx.x;
  for (int i = tid; i < O_DIM * N_DIM; i += 256) w2s[i] = W2[i];
  __syncthreads();

  int wave = tid >> 6;
  int lane = tid & 63;
  int b = blockIdx.x * 4 + wave;
  const float* hrow = h + (size_t)b * (T_DIM * N_DIM);
  float* orow = out + (size_t)b * (T_DIM * O_DIM);

  float v1[16];
  #pragma unroll
  for (int e = 0; e < 16; ++e) v1[e] = 0.f;
  float v2 = 0.f;
  float bias2 = (lane < O_DIM) ? b2[lane] : 0.f;

  floatx4 hv[4];
  #pragma unroll
  for (int c = 0; c < 4; ++c) hv[c] = *(const floatx4*)(hrow + c * 256 + lane * 4);

  for (int t = 0; t < T_DIM; ++t) {
    floatx4 hn[4];
    if (t + 1 < T_DIM) {
      #pragma unroll
      for (int c = 0; c < 4; ++c)
        hn[c] = *(const floatx4*)(hrow + (t + 1) * N_DIM + c * 256 + lane * 4);
    }

    float sarr[16];
    #pragma unroll
    for (int c = 0; c < 4; ++c) {
      #pragma unroll
      for (int e = 0; e < 4; ++e) {
        int ii = c * 4 + e;
        float vn = 0.9f * v1[ii] + hv[c][e];
        float s  = 1.f / (1.f + __expf(10.f - 10.f * vn));
        v1[ii] = vn * (1.f - s);
        sarr[ii] = s;
      }
    }

    float part[10];
    #pragma unroll
    for (int o = 0; o < O_DIM; ++o) {
      float a = 0.f;
      #pragma unroll
      for (int c = 0; c < 4; ++c) {
        floatx4 w4 = *(const floatx4*)&w2s[o * N_DIM + c * 256 + lane * 4];
        a += sarr[c * 4 + 0] * w4[0] + sarr[c * 4 + 1] * w4[1]
           + sarr[c * 4 + 2] * w4[2] + sarr[c * 4 + 3] * w4[3];
      }
      part[o] = a;
    }
    #pragma unroll
    for (int m = 1; m < 64; m <<= 1) {
      #pragma unroll
      for (int o = 0; o < O_DIM; ++o) part[o] += __shfl_xor(part[o], m, 64);
    }

    float po = part[0];
    #pragma unroll
    for (int o = 1; o < O_DIM; ++o) po = (lane == o) ? part[o] : po;

    if (lane < O_DIM) {
      float vo = 0.9f * v2 + po + bias2;
      float s2 = 1.f / (1.f + __expf(10.f - 10.f * vo));
      v2 = vo * (1.f - s2);
      orow[t * O_DIM + lane] = s2;
    }

    #pragma unroll
    for (int c = 0; c < 4; ++c) hv[c] = hn[c];
  }
}

extern "C" void kernel_launch(void* const* d_in, const int* in_sizes, int n_in,
                              void* d_out, int out_size, void* d_ws, size_t ws_size,
                              hipStream_t stream) {
  const float* x  = (const float*)d_in[0];
  const float* W1 = (const float*)d_in[1];
  const float* b1 = (const float*)d_in[2];
  const float* W2 = (const float*)d_in[3];
  const float* b2 = (const float*)d_in[4];
  float* out = (float*)d_out;

  float* h = (float*)d_ws;  // 64 MiB

  const size_t H_BYTES  = (size_t)M_DIM * N_DIM * 4;   // 67,108,864
  const size_t WH_BYTES = (size_t)N_DIM * KP * 2;      //  4,849,664
  const size_t NEED = H_BYTES + WH_BYTES;

  if (ws_size >= NEED) {
    _Float16* w1h = (_Float16*)((char*)d_ws + H_BYTES);
    cvt_f32_f16_pad<<<dim3(N_DIM), dim3(256), 0, stream>>>(W1, w1h);
    gemm_fused4<<<dim3(256), dim3(512), 0, stream>>>(x, w1h, b1, h);
  } else {
    gemm1_kernel<<<dim3(1024), dim3(256), 0, stream>>>(x, W1, b1, h);
  }
  snn_temporal_kernel<<<dim3(256), dim3(256), 0, stream>>>(h, W2, b2, out);
}

// Round 10
// 128.628 us; speedup vs baseline: 1.2365x; 1.2365x over previous
//
#include <hip/hip_runtime.h>

typedef _Float16 half8  __attribute__((ext_vector_type(8)));
typedef _Float16 half4v __attribute__((ext_vector_type(4)));
typedef float    floatx4 __attribute__((ext_vector_type(4)));

#define K_DIM 2312
#define KP    2368          // W1 fp16 padded K (74*32)
#define N_DIM 1024
#define M_DIM 16384
#define T_DIM 16
#define O_DIM 10
#define NKT   73            // BK=32 tiles covering 2312 (tile 72 partial)
#define NT_OLD 73
#define LDP 40

// =====================================================================
// cvt: fp32 -> fp16 with K zero-pad to 2368 (W1 only; pad MUST be zero --
// tile-72 A garbage relies on B==0 for k in [2312,2336))
// =====================================================================
__global__ __launch_bounds__(256) void cvt_f32_f16_pad(const float* __restrict__ src,
                                                       _Float16* __restrict__ dst) {
  int row = blockIdx.x;
  const float* s = src + (size_t)row * K_DIM;
  _Float16* d = dst + (size_t)row * KP;
  for (int c = threadIdx.x; c < 296; c += 256) {
    half8 o;
    if (c < 289) {
      floatx4 a = *(const floatx4*)(s + c * 8);
      floatx4 b = *(const floatx4*)(s + c * 8 + 4);
      #pragma unroll
      for (int e = 0; e < 4; ++e) { o[e] = (_Float16)a[e]; o[4 + e] = (_Float16)b[e]; }
    } else {
      o = half8{0, 0, 0, 0, 0, 0, 0, 0};
    }
    *(half8*)(d + c * 8) = o;
  }
}

// =====================================================================
// GEMM + fused LIF layer 1:
//   h = x(fp32) @ w1h^T + b1 ; s1 = LIF(h over t) -> fp16
// Main loop = R8's proven ring VERBATIM: 256x256, BK=32, 8 waves (4Mx2N),
// A raw fp32 via global_load_lds (pure vmcnt), 3A+3B slots, stage 2 ahead,
// vmcnt(6), ONE barrier/tile, M-first (MFMA(t) then READF(t+1)).
// Epilogue: 256-row tile = 16 batches x 16 timesteps -> layer-1 LIF
// recurrence closes in-block. Per j-chunk: acc -> LDS[256][33] ->
// thread-per-(b,col) chain -> s1 fp16.
// =====================================================================
__device__ __forceinline__ void gload16(const void* g, void* l) {
  __builtin_amdgcn_global_load_lds((const __attribute__((address_space(1))) void*)g,
                                   (__attribute__((address_space(3))) void*)l, 16, 0, 0);
}

#define VMCNT(n)  asm volatile("s_waitcnt vmcnt(" #n ")" ::: "memory")
#define SBAR      __builtin_amdgcn_sched_barrier(0)

__global__ __launch_bounds__(512, 2) void gemm_lif1(const float* __restrict__ X,
                                                    const _Float16* __restrict__ Bw,
                                                    const float* __restrict__ b1,
                                                    _Float16* __restrict__ s1) {
  __shared__ __align__(16) float    As[3][256 * 32];   // 3 x 32 KiB (fp32 A)
  __shared__ __align__(16) _Float16 Bs[3][256 * 32];   // 3 x 16 KiB (fp16 B)

  const int tid  = threadIdx.x;
  const int lane = tid & 63;
  const int w    = tid >> 6;          // 0..7
  const int wm   = (w >> 1) * 64;     // 4 row-waves
  const int wn   = (w & 1) * 128;     // 2 col-waves
  const int bm   = blockIdx.x & 63;
  const int bn   = blockIdx.x >> 6;
  const int m0   = bm * 256;
  const int n0   = bn * 256;

  // ---- A staging: 4 DMAs/thread; DMA d covers rows [w*32+d*8, +8) ----
  const int rOffA = lane >> 3;
  const int gsrcA = (lane & 7) ^ (lane >> 3);        // pre-swizzled granule
  const float* xaw = X + (size_t)(m0 + w * 32) * K_DIM;   // wave base

  // ---- B staging (proven R5 pattern) ----
  const int rlo  = lane >> 2;
  const int keyB = (rlo >> 1) & 3;
  const int cch  = (lane & 3) ^ keyB;
  const _Float16* bg = Bw + (size_t)(n0 + w * 32 + rlo) * KP + cch * 8;
  const int stbB = (w * 32) * 32;

  floatx4 acc[4][8];
  #pragma unroll
  for (int i = 0; i < 4; ++i)
    #pragma unroll
    for (int j = 0; j < 8; ++j)
      acc[i][j] = floatx4{0.f, 0.f, 0.f, 0.f};

  // ---- fragment read offsets ----
  const int fr = lane & 15;
  const int q  = lane >> 4;           // 0..3
  const int rdsB = (q ^ ((fr >> 1) & 3)) * 8;        // B swizzled 16B slot (halfs)
  int offB[8];
  #pragma unroll
  for (int j = 0; j < 8; ++j) offB[j] = (wn + j * 16 + fr) * 32 + rdsB;
  const int cA = fr & 7;
  int offA0[4], offA1[4];
  #pragma unroll
  for (int i = 0; i < 4; ++i) {
    const int rowA = wm + i * 16 + fr;
    offA0[i] = rowA * 32 + ((2 * q)     ^ cA) * 4;   // floats
    offA1[i] = rowA * 32 + ((2 * q + 1) ^ cA) * 4;
  }

  floatx4 fA[8];     // raw fp32 A frags (frag i = fA[2i], fA[2i+1])
  half8   bf[8];

#define STAGE(tk) do {                                                       \
    const int _s = (tk) % 3;                                                 \
    _Pragma("unroll")                                                        \
    for (int _d = 0; _d < 4; ++_d) {                                         \
      int _k = (tk) * 32 + gsrcA * 4;                                        \
      _k = _k > 2308 ? 2308 : _k;                                            \
      const float* _src = xaw + (size_t)(_d * 8 + rOffA) * K_DIM + _k;       \
      gload16(_src, &As[_s][(w * 32 + _d * 8) * 32]);                        \
    }                                                                        \
    gload16(bg + (tk) * 32,           &Bs[_s][stbB]);                        \
    gload16(bg + (tk) * 32 + 16 * KP, &Bs[_s][stbB + 16 * 32]);              \
  } while (0)

#define READF(tk) do {                                                       \
    const float*    _A = As[(tk) % 3];                                       \
    const _Float16* _B = Bs[(tk) % 3];                                       \
    _Pragma("unroll")                                                        \
    for (int _i = 0; _i < 4; ++_i) {                                         \
      fA[2 * _i]     = *(const floatx4*)(&_A[offA0[_i]]);                    \
      fA[2 * _i + 1] = *(const floatx4*)(&_A[offA1[_i]]);                    \
    }                                                                        \
    _Pragma("unroll")                                                        \
    for (int _j = 0; _j < 8; ++_j) bf[_j] = *(const half8*)(&_B[offB[_j]]);  \
  } while (0)

#define MFMA32 do {                                                          \
    __builtin_amdgcn_s_setprio(1);                                           \
    _Pragma("unroll")                                                        \
    for (int _i = 0; _i < 4; ++_i) {                                         \
      half8 _ah;                                                             \
      _Pragma("unroll")                                                      \
      for (int _e = 0; _e < 4; ++_e) {                                       \
        _ah[_e]     = (_Float16)fA[2 * _i][_e];                              \
        _ah[4 + _e] = (_Float16)fA[2 * _i + 1][_e];                          \
      }                                                                      \
      _Pragma("unroll")                                                      \
      for (int _j = 0; _j < 8; ++_j)                                         \
        acc[_i][_j] = __builtin_amdgcn_mfma_f32_16x16x32_f16(_ah, bf[_j], acc[_i][_j], 0, 0, 0); \
    }                                                                        \
    __builtin_amdgcn_s_setprio(0);                                           \
  } while (0)

  // ---- prologue: stage tiles 0,1 (12 DMAs); publish tile 0; read frags ----
  STAGE(0); STAGE(1);
  VMCNT(6); SBAR;              // tile 0's 6 ops retired
  __builtin_amdgcn_s_barrier(); SBAR;
  READF(0);

  // ---- main loop: t = 0..70 (stages t+2 = 2..72) ----
  for (int t = 0; t < NKT - 2; ++t) {
    STAGE(t + 2);              // slot (t+2)%3 == (t-1)%3: reads retired an iter ago
    VMCNT(6); SBAR;            // retire tile t+1's 6 ops
    __builtin_amdgcn_s_barrier(); SBAR;   // publish tile t+1
    MFMA32;                    // tile t (frags read last iter)
    READF(t + 1);              // reads drain under next front / MFMA tail
  }

  // ---- tail: t = 71 ----
  VMCNT(0); SBAR;              // tile 72 landed
  __builtin_amdgcn_s_barrier(); SBAR;
  MFMA32;                      // tile 71
  READF(NKT - 1);              // tile 72
  MFMA32;                      // tile 72

#undef STAGE
#undef READF
#undef MFMA32

  // ================= epilogue: fused LIF layer-1 =================
  // acc[i][j][e]: row_local = wm + i*16 + 4q + e (= b_local*16 + t),
  // col = n0 + wn + j*16 + fr. Per j-chunk: acc -> ch[256][33] ->
  // each thread owns one (b_local, ci) chain over t=0..15 -> s1 fp16.
  float* ch = (float*)As;               // 256*33*4 = 33792 B, fits in As
  const int colIdx = (w & 1) * 16 + fr; // 0..31 within chunk
  const int bloc = tid >> 5;            // 0..15
  const int ci   = tid & 31;            // 0..31
  const int gcolBase = n0 + (ci >> 4) * 128 + (ci & 15);

  #pragma unroll
  for (int j = 0; j < 8; ++j) {
    __syncthreads();                    // ch free (main loop / prev chunk done)
    #pragma unroll
    for (int i = 0; i < 4; ++i) {
      const int rl = wm + i * 16 + 4 * q;
      #pragma unroll
      for (int e = 0; e < 4; ++e)
        ch[(rl + e) * 33 + colIdx] = acc[i][j][e];
    }
    __syncthreads();
    const int gcol = gcolBase + j * 16;
    const float bv = b1[gcol];
    float hv[16];
    #pragma unroll
    for (int t = 0; t < 16; ++t) hv[t] = ch[(bloc * 16 + t) * 33 + ci];
    float v = 0.f;
    _Float16* srow = s1 + (size_t)(m0 + bloc * 16) * N_DIM + gcol;
    #pragma unroll
    for (int t = 0; t < 16; ++t) {
      float vn = 0.9f * v + hv[t] + bv;
      float s  = 1.f / (1.f + __expf(10.f - 10.f * vn));
      v = vn * (1.f - s);
      srow[(size_t)t * N_DIM] = (_Float16)s;
    }
  }
}

// =====================================================================
// Phase C: layer-2 only (s1 fp16 in), one wave per batch row
// =====================================================================
__global__ __launch_bounds__(256) void snn_layer2_kernel(const _Float16* __restrict__ s1,
                                                         const float* __restrict__ W2,
                                                         const float* __restrict__ b2,
                                                         float* __restrict__ out) {
  __shared__ float w2s[O_DIM * N_DIM];   // 40 KB
  int tid = threadIdx.x;
  for (int i = tid; i < O_DIM * N_DIM; i += 256) w2s[i] = W2[i];
  __syncthreads();

  int wave = tid >> 6;
  int lane = tid & 63;
  int b = blockIdx.x * 4 + wave;
  const _Float16* srow = s1 + (size_t)b * (T_DIM * N_DIM) + lane * 16;
  float* orow = out + (size_t)b * (T_DIM * O_DIM);

  float v2 = 0.f;
  float bias2 = (lane < O_DIM) ? b2[lane] : 0.f;

  half8 p0 = *(const half8*)(srow);
  half8 p1 = *(const half8*)(srow + 8);

  for (int t = 0; t < T_DIM; ++t) {
    half8 n0h, n1h;
    if (t + 1 < T_DIM) {
      n0h = *(const half8*)(srow + (t + 1) * N_DIM);
      n1h = *(const half8*)(srow + (t + 1) * N_DIM + 8);
    }

    float sv[16];
    #pragma unroll
    for (int e = 0; e < 8; ++e) { sv[e] = (float)p0[e]; sv[8 + e] = (float)p1[e]; }

    float part[O_DIM];
    #pragma unroll
    for (int o = 0; o < O_DIM; ++o) {
      float a = 0.f;
      #pragma unroll
      for (int c = 0; c < 4; ++c) {
        floatx4 w4 = *(const floatx4*)&w2s[o * N_DIM + lane * 16 + c * 4];
        a += sv[c * 4 + 0] * w4[0] + sv[c * 4 + 1] * w4[1]
           + sv[c * 4 + 2] * w4[2] + sv[c * 4 + 3] * w4[3];
      }
      part[o] = a;
    }
    #pragma unroll
    for (int m = 1; m < 64; m <<= 1) {
      #pragma unroll
      for (int o = 0; o < O_DIM; ++o) part[o] += __shfl_xor(part[o], m, 64);
    }

    float po = part[0];
    #pragma unroll
    for (int o = 1; o < O_DIM; ++o) po = (lane == o) ? part[o] : po;

    if (lane < O_DIM) {
      float vo = 0.9f * v2 + po + bias2;
      float s2 = 1.f / (1.f + __expf(10.f - 10.f * vo));
      v2 = vo * (1.f - s2);
      orow[t * O_DIM + lane] = s2;
    }

    p0 = n0h; p1 = n1h;
  }
}

// =====================================================================
// Fallback (R1): reg-staged fp32->fp16 GEMM + old fused LIF, if ws small
// =====================================================================
__device__ __forceinline__ void stage_load(const float* __restrict__ x,
                                           const float* __restrict__ w,
                                           int m0, int n0, int k0, int tid,
                                           floatx4 (&ar)[4], floatx4 (&br)[4]) {
  int r = tid >> 3;
  int c = (tid & 7) * 4;
  bool ok = (k0 + c) < K_DIM;
  #pragma unroll
  for (int i = 0; i < 4; ++i) {
    int row = r + 32 * i;
    if (ok) {
      ar[i] = *(const floatx4*)(x + (size_t)(m0 + row) * K_DIM + k0 + c);
      br[i] = *(const floatx4*)(w + (size_t)(n0 + row) * K_DIM + k0 + c);
    } else {
      ar[i] = floatx4{0.f, 0.f, 0.f, 0.f};
      br[i] = floatx4{0.f, 0.f, 0.f, 0.f};
    }
  }
}

__device__ __forceinline__ void stage_write(_Float16* __restrict__ Ab,
                                            _Float16* __restrict__ Bb, int tid,
                                            const floatx4 (&ar)[4], const floatx4 (&br)[4]) {
  int r = tid >> 3;
  int c = (tid & 7) * 4;
  #pragma unroll
  for (int i = 0; i < 4; ++i) {
    int row = r + 32 * i;
    half4v av, bv;
    #pragma unroll
    for (int e = 0; e < 4; ++e) {
      av[e] = (_Float16)ar[i][e];
      bv[e] = (_Float16)br[i][e];
    }
    *(half4v*)(Ab + row * LDP + c) = av;
    *(half4v*)(Bb + row * LDP + c) = bv;
  }
}

__global__ __launch_bounds__(256) void gemm1_kernel(const float* __restrict__ x,
                                                    const float* __restrict__ W1,
                                                    const float* __restrict__ b1,
                                                    float* __restrict__ h) {
  __shared__ _Float16 Al[2][128 * LDP];
  __shared__ _Float16 Bl[2][128 * LDP];

  int tid  = threadIdx.x;
  int lane = tid & 63;
  int w    = tid >> 6;
  int wm   = (w >> 1) * 64;
  int wn   = (w & 1) * 64;
  int m0   = (blockIdx.x >> 3) * 128;
  int n0   = (blockIdx.x & 7) * 128;

  floatx4 acc[4][4];
  #pragma unroll
  for (int i = 0; i < 4; ++i)
    #pragma unroll
    for (int j = 0; j < 4; ++j)
      acc[i][j] = floatx4{0.f, 0.f, 0.f, 0.f};

  floatx4 ar[4], br[4];
  stage_load(x, W1, m0, n0, 0, tid, ar, br);
  stage_write(Al[0], Bl[0], tid, ar, br);
  __syncthreads();

  int fr = lane & 15;
  int kc = (lane >> 4) * 8;

  int cur = 0;
  for (int kt = 0; kt < NT_OLD; ++kt) {
    if (kt + 1 < NT_OLD) stage_load(x, W1, m0, n0, (kt + 1) * 32, tid, ar, br);

    const _Float16* Ab = Al[cur];
    const _Float16* Bb = Bl[cur];
    half8 af[4], bf[4];
    #pragma unroll
    for (int f = 0; f < 4; ++f) {
      af[f] = *(const half8*)(Ab + (wm + f * 16 + fr) * LDP + kc);
      bf[f] = *(const half8*)(Bb + (wn + f * 16 + fr) * LDP + kc);
    }
    #pragma unroll
    for (int i = 0; i < 4; ++i)
      #pragma unroll
      for (int j = 0; j < 4; ++j)
        acc[i][j] = __builtin_amdgcn_mfma_f32_16x16x32_f16(af[i], bf[j], acc[i][j], 0, 0, 0);

    if (kt + 1 < NT_OLD) stage_write(Al[cur ^ 1], Bl[cur ^ 1], tid, ar, br);
    __syncthreads();
    cur ^= 1;
  }

  int cr = (lane >> 4) * 4;
  #pragma unroll
  for (int j = 0; j < 4; ++j) {
    int col = n0 + wn + j * 16 + fr;
    float bv = b1[col];
    #pragma unroll
    for (int i = 0; i < 4; ++i) {
      int rbase = m0 + wm + i * 16 + cr;
      #pragma unroll
      for (int e = 0; e < 4; ++e)
        h[(size_t)(rbase + e) * N_DIM + col] = acc[i][j][e] + bv;
    }
  }
}

__global__ __launch_bounds__(256) void snn_temporal_kernel(const float* __restrict__ h,
                                                           const float* __restrict__ W2,
                                                           const float* __restrict__ b2,
                                                           float* __restrict__ out) {
  __shared__ float w2s[O_DIM * N_DIM];   // 40 KB
  int tid = threadIdx.x;
  for (int i = tid; i < O_DIM * N_DIM; i += 256) w2s[i] = W2[i];
  __syncthreads();

  int wave = tid >> 6;
  int lane = tid & 63;
  int b = blockIdx.x * 4 + wave;
  const float* hrow = h + (size_t)b * (T_DIM * N_DIM);
  float* orow = out + (size_t)b * (T_DIM * O_DIM);

  float v1[16];
  #pragma unroll
  for (int e = 0; e < 16; ++e) v1[e] = 0.f;
  float v2 = 0.f;
  float bias2 = (lane < O_DIM) ? b2[lane] : 0.f;

  floatx4 hv[4];
  #pragma unroll
  for (int c = 0; c < 4; ++c) hv[c] = *(const floatx4*)(hrow + c * 256 + lane * 4);

  for (int t = 0; t < T_DIM; ++t) {
    floatx4 hn[4];
    if (t + 1 < T_DIM) {
      #pragma unroll
      for (int c = 0; c < 4; ++c)
        hn[c] = *(const floatx4*)(hrow + (t + 1) * N_DIM + c * 256 + lane * 4);
    }

    float sarr[16];
    #pragma unroll
    for (int c = 0; c < 4; ++c) {
      #pragma unroll
      for (int e = 0; e < 4; ++e) {
        int ii = c * 4 + e;
        float vn = 0.9f * v1[ii] + hv[c][e];
        float s  = 1.f / (1.f + __expf(10.f - 10.f * vn));
        v1[ii] = vn * (1.f - s);
        sarr[ii] = s;
      }
    }

    float part[10];
    #pragma unroll
    for (int o = 0; o < O_DIM; ++o) {
      float a = 0.f;
      #pragma unroll
      for (int c = 0; c < 4; ++c) {
        floatx4 w4 = *(const floatx4*)&w2s[o * N_DIM + c * 256 + lane * 4];
        a += sarr[c * 4 + 0] * w4[0] + sarr[c * 4 + 1] * w4[1]
           + sarr[c * 4 + 2] * w4[2] + sarr[c * 4 + 3] * w4[3];
      }
      part[o] = a;
    }
    #pragma unroll
    for (int m = 1; m < 64; m <<= 1) {
      #pragma unroll
      for (int o = 0; o < O_DIM; ++o) part[o] += __shfl_xor(part[o], m, 64);
    }

    float po = part[0];
    #pragma unroll
    for (int o = 1; o < O_DIM; ++o) po = (lane == o) ? part[o] : po;

    if (lane < O_DIM) {
      float vo = 0.9f * v2 + po + bias2;
      float s2 = 1.f / (1.f + __expf(10.f - 10.f * vo));
      v2 = vo * (1.f - s2);
      orow[t * O_DIM + lane] = s2;
    }

    #pragma unroll
    for (int c = 0; c < 4; ++c) hv[c] = hn[c];
  }
}

extern "C" void kernel_launch(void* const* d_in, const int* in_sizes, int n_in,
                              void* d_out, int out_size, void* d_ws, size_t ws_size,
                              hipStream_t stream) {
  const float* x  = (const float*)d_in[0];
  const float* W1 = (const float*)d_in[1];
  const float* b1 = (const float*)d_in[2];
  const float* W2 = (const float*)d_in[3];
  const float* b2 = (const float*)d_in[4];
  float* out = (float*)d_out;

  const size_t S1_BYTES = (size_t)M_DIM * N_DIM * 2;   // 33,554,432
  const size_t WH_BYTES = (size_t)N_DIM * KP * 2;      //  4,849,664
  const size_t NEED = S1_BYTES + WH_BYTES;

  if (ws_size >= NEED) {
    _Float16* s1h = (_Float16*)d_ws;
    _Float16* w1h = (_Float16*)((char*)d_ws + S1_BYTES);
    cvt_f32_f16_pad<<<dim3(N_DIM), dim3(256), 0, stream>>>(W1, w1h);
    gemm_lif1<<<dim3(256), dim3(512), 0, stream>>>(x, w1h, b1, s1h);
    snn_layer2_kernel<<<dim3(256), dim3(256), 0, stream>>>(s1h, W2, b2, out);
  } else {
    float* h = (float*)d_ws;  // 64 MiB
    gemm1_kernel<<<dim3(1024), dim3(256), 0, stream>>>(x, W1, b1, h);
    snn_temporal_kernel<<<dim3(256), dim3(256), 0, stream>>>(h, W2, b2, out);
  }
}